// Round 1
// baseline (893.621 us; speedup 1.0000x reference)
//
#include <hip/hip_runtime.h>
#include <math.h>

// ---------------------------------------------------------------------------
// Bidirectional Mamba encoder (S-Mamba style), fp32 baseline.
// B=8, L=1031 tokens (1024 vars + 7 marks), DM=DIN=128, DSTATE=16, DTR=8,
// DCONV=2, EL=2, DFF=128, PRED=96.
// Pipeline per call (12 launches):
//   k_embed -> H
//   for l in {0,1}: k_xz -> XZ ; k_mid -> xcT/deltaT/BmT/CmT ; k_scan -> YT ;
//                   k_out -> H1 (residual+norm1) ; k_ffn -> H (ffn+norm2)
//   k_final -> d_out (fnorm + proj + transpose)
// Workspace: ~50.4 MiB fp32 (layout below).
// ---------------------------------------------------------------------------

#define L_SEQ 1031
#define LP    1032   // t padded to multiple of 4 for float4 scan streaming
#define BATCH 8
#define NVAR  1024
#define SEQQ  512
#define TFEAT 7

// workspace offsets (in floats)
#define SZ_H    ((size_t)BATCH * L_SEQ * 128)       // 1,055,744
#define SZ_XZ   ((size_t)2 * BATCH * L_SEQ * 256)   // 4,222,976
#define SZ_DT   ((size_t)2 * BATCH * 128 * LP)      // 2,113,536
#define SZ_BC   ((size_t)2 * BATCH * 16 * LP)       //   264,192
#define OFF_H    ((size_t)0)
#define OFF_H1   (OFF_H + SZ_H)
#define OFF_XZ   (OFF_H1 + SZ_H)
#define OFF_XCT  (OFF_XZ + SZ_XZ)
#define OFF_DLT  (OFF_XCT + SZ_DT)
#define OFF_BMT  (OFF_DLT + SZ_DT)
#define OFF_CMT  (OFF_BMT + SZ_BC)
#define OFF_YT   (OFF_CMT + SZ_BC)
// total = OFF_YT + SZ_DT = 13,203,456 floats = 50.4 MiB

__device__ __forceinline__ float silu_f(float x) {
  return x / (1.f + __expf(-x));
}
__device__ __forceinline__ float softplus_f(float x) {
  return (x > 20.f) ? x : log1pf(__expf(x));
}

// ---------------------------------------------------------------------------
// k_embed: H[b,v,:] = token(b,v,:) @ emb_w.T + emb_b
// token(b,v,s) = v<1024 ? fix(x_enc[b,s,v]) : x_mark[b,s,v-1024]
// grid (33, 8), block 256. Tile 32 rows x 128 cols, BK=32.
// ---------------------------------------------------------------------------
__global__ __launch_bounds__(256) void k_embed(
    const float* __restrict__ x_enc, const float* __restrict__ x_mark,
    const float* __restrict__ emb_w, const float* __restrict__ emb_b,
    float* __restrict__ H) {
  int b = blockIdx.y;
  int v0 = blockIdx.x * 32;
  int tid = threadIdx.x;
  __shared__ float As[32][33];    // [k(s)][row(v)]
  __shared__ float Ws[32][144];   // [k(s)][m]  stride 144 -> 2-way banks (free)
  int tm = tid & 15, tt = tid >> 4;
  float acc[2][8] = {{0.f}};
  for (int s0 = 0; s0 < SEQQ; s0 += 32) {
    for (int i = 0; i < 4; i++) {
      int e = tid + i * 256;
      int vi = e & 31, si = e >> 5;
      int v = v0 + vi, s = s0 + si;
      float val = 0.f;
      if (v < L_SEQ) {
        if (v < NVAR) {
          val = x_enc[((size_t)b * SEQQ + s) * NVAR + v];
          if (val == -9999.f) val = -1.f;
        } else {
          val = x_mark[((size_t)b * SEQQ + s) * TFEAT + (v - NVAR)];
        }
      }
      As[si][vi] = val;
    }
    for (int i = 0; i < 16; i++) {
      int e = tid + i * 256;
      int si = e & 31, m = e >> 5;
      Ws[si][m] = emb_w[(size_t)m * SEQQ + s0 + si];
    }
    __syncthreads();
    for (int si = 0; si < 32; si++) {
      float a0 = As[si][tt * 2], a1 = As[si][tt * 2 + 1];
      float w[8];
      *(float4*)&w[0] = *(const float4*)&Ws[si][tm * 8];
      *(float4*)&w[4] = *(const float4*)&Ws[si][tm * 8 + 4];
#pragma unroll
      for (int j = 0; j < 8; j++) {
        acc[0][j] = fmaf(a0, w[j], acc[0][j]);
        acc[1][j] = fmaf(a1, w[j], acc[1][j]);
      }
    }
    __syncthreads();
  }
#pragma unroll
  for (int r = 0; r < 2; r++) {
    int v = v0 + tt * 2 + r;
    if (v < L_SEQ) {
      float* dst = &H[((size_t)b * L_SEQ + v) * 128 + tm * 8];
#pragma unroll
      for (int j = 0; j < 8; j++) dst[j] = acc[r][j] + emb_b[tm * 8 + j];
    }
  }
}

// ---------------------------------------------------------------------------
// k_xz: XZ[dir,b,t,:256] = h_dir(b,t,:) @ ipw[l,dir].T
// h_fwd(t) = H[b,t], h_rev(t) = H[b,L-1-t]
// grid (33, 8, 2), block 256. Tile 32 x 256, BK=32.
// ---------------------------------------------------------------------------
__global__ __launch_bounds__(256) void k_xz(
    const float* __restrict__ H, const float* __restrict__ ipw,
    float* __restrict__ XZ, int l) {
  int b = blockIdx.y, dir = blockIdx.z;
  int t0 = blockIdx.x * 32;
  int tid = threadIdx.x;
  __shared__ float As[32][33];
  __shared__ float Ws[32][272];   // 272 % 32 = 16 -> 2-way (free)
  int tm = tid & 15, tt = tid >> 4;
  float acc[2][16] = {{0.f}};
  const float* wbase = ipw + (size_t)(l * 2 + dir) * 256 * 128;
  for (int k0 = 0; k0 < 128; k0 += 32) {
    for (int i = 0; i < 4; i++) {
      int e = tid + i * 256;
      int ki = e & 31, tl = e >> 5;
      int t = t0 + tl;
      float v = 0.f;
      if (t < L_SEQ) {
        int st = dir ? (L_SEQ - 1 - t) : t;
        v = H[((size_t)b * L_SEQ + st) * 128 + k0 + ki];
      }
      As[ki][tl] = v;
    }
    for (int i = 0; i < 32; i++) {
      int e = tid + i * 256;
      int ki = e & 31, j = e >> 5;
      Ws[ki][j] = wbase[(size_t)j * 128 + k0 + ki];
    }
    __syncthreads();
    for (int ki = 0; ki < 32; ki++) {
      float a0 = As[ki][tt * 2], a1 = As[ki][tt * 2 + 1];
      float w[16];
      *(float4*)&w[0]  = *(const float4*)&Ws[ki][tm * 16];
      *(float4*)&w[4]  = *(const float4*)&Ws[ki][tm * 16 + 4];
      *(float4*)&w[8]  = *(const float4*)&Ws[ki][tm * 16 + 8];
      *(float4*)&w[12] = *(const float4*)&Ws[ki][tm * 16 + 12];
#pragma unroll
      for (int j = 0; j < 16; j++) {
        acc[0][j] = fmaf(a0, w[j], acc[0][j]);
        acc[1][j] = fmaf(a1, w[j], acc[1][j]);
      }
    }
    __syncthreads();
  }
#pragma unroll
  for (int r = 0; r < 2; r++) {
    int t = t0 + tt * 2 + r;
    if (t < L_SEQ) {
      float* dst = XZ + ((size_t)(dir * BATCH + b) * L_SEQ + t) * 256 + tm * 16;
#pragma unroll
      for (int j = 0; j < 16; j++) dst[j] = acc[r][j];
    }
  }
}

// ---------------------------------------------------------------------------
// k_mid: conv1d(DCONV=2)+silu -> xc ; dbc = xc @ xpw.T ; delta=softplus(dt@dpw.T+dpb)
// writes xcT[dir,b,d,t], deltaT[dir,b,d,t], BmT/CmT[dir,b,n,t]
// grid (17, 8, 2), block 256, 64-t tiles.
// ---------------------------------------------------------------------------
__global__ __launch_bounds__(256) void k_mid(
    const float* __restrict__ XZ,
    const float* __restrict__ conv_w, const float* __restrict__ conv_b,
    const float* __restrict__ xpw,
    const float* __restrict__ dpw, const float* __restrict__ dpb,
    float* __restrict__ XCT, float* __restrict__ DLT,
    float* __restrict__ BmT, float* __restrict__ CmT, int l) {
  int b = blockIdx.y, dir = blockIdx.z;
  int t0 = blockIdx.x * 64;
  int tid = threadIdx.x;
  int pg = l * 2 + dir;
  __shared__ float xcs[64][132];   // 33,792 B
  __shared__ float xpws[40][128];  // 20,480 B (reads are broadcast)
  __shared__ float dbcs[40][68];   // 10,880 B   total 65,152 <= 64 KiB
  const float* xz = XZ + (size_t)(dir * BATCH + b) * L_SEQ * 256;

  for (int i = 0; i < 20; i++) {
    int e = tid + i * 256;
    int k = e & 127, j = e >> 7;
    xpws[j][k] = xpw[((size_t)pg * 40 + j) * 128 + k];
  }
  for (int i = 0; i < 32; i++) {
    int e = tid + i * 256;
    int d = e & 127, tl = e >> 7;
    int t = t0 + tl;
    float v = 0.f;
    if (t < L_SEQ) {
      float x1 = xz[(size_t)t * 256 + d];
      float x0 = (t > 0) ? xz[(size_t)(t - 1) * 256 + d] : 0.f;
      float c0 = conv_w[((size_t)pg * 128 + d) * 2 + 0];
      float c1 = conv_w[((size_t)pg * 128 + d) * 2 + 1];
      float pre = x0 * c0 + x1 * c1 + conv_b[(size_t)pg * 128 + d];
      v = silu_f(pre);
    }
    xcs[tl][d] = v;
  }
  __syncthreads();
  // dbc = xc @ xpw.T   (64 t x 40 j, K=128)
  {
    int tl = tid & 63, jg = tid >> 6;
    float acc[10] = {0.f};
    const float4* xrow = (const float4*)&xcs[tl][0];
    for (int kk = 0; kk < 32; kk++) {
      float4 a = xrow[kk];
#pragma unroll
      for (int jj = 0; jj < 10; jj++) {
        float4 w = ((const float4*)&xpws[jg * 10 + jj][0])[kk];
        acc[jj] = fmaf(a.x, w.x, acc[jj]);
        acc[jj] = fmaf(a.y, w.y, acc[jj]);
        acc[jj] = fmaf(a.z, w.z, acc[jj]);
        acc[jj] = fmaf(a.w, w.w, acc[jj]);
      }
    }
#pragma unroll
    for (int jj = 0; jj < 10; jj++) dbcs[jg * 10 + jj][tl] = acc[jj];
  }
  __syncthreads();
  // Bm/Cm transposed stores
  for (int i = 0; i < 8; i++) {
    int e = tid + i * 256;
    int tl = e & 63, r = e >> 6;      // r in 0..31
    int n = r & 15, isC = r >> 4;
    int t = t0 + tl;
    if (t < LP) {
      float v = dbcs[8 + isC * 16 + n][tl];
      float* dst = isC ? CmT : BmT;
      dst[((size_t)(dir * BATCH + b) * 16 + n) * LP + t] = v;
    }
  }
  // delta = softplus(dt @ dpw.T + dpb), transposed stores; xcT stores
  {
    int d = tid & 127, th = tid >> 7;
    float dw[8];
#pragma unroll
    for (int k = 0; k < 8; k++) dw[k] = dpw[((size_t)pg * 128 + d) * 8 + k];
    float dbv = dpb[(size_t)pg * 128 + d];
    size_t base = ((size_t)(dir * BATCH + b) * 128 + d) * LP;
    for (int tb = th * 32; tb < th * 32 + 32; tb += 4) {
      int t = t0 + tb;
      if (t < LP) {   // t multiple of 4, LP multiple of 4 -> whole float4 in range
        float dv[4], xv[4];
#pragma unroll
        for (int u = 0; u < 4; u++) {
          int tl = tb + u;
          float a = dbv;
#pragma unroll
          for (int k = 0; k < 8; k++) a = fmaf(dbcs[k][tl], dw[k], a);
          dv[u] = softplus_f(a);
          xv[u] = xcs[tl][d];
        }
        *(float4*)(DLT + base + t) = make_float4(dv[0], dv[1], dv[2], dv[3]);
        *(float4*)(XCT + base + t) = make_float4(xv[0], xv[1], xv[2], xv[3]);
      }
    }
  }
}

// ---------------------------------------------------------------------------
// k_scan: selective scan. One wave per (8 d x 16 n); lane = dsub*8 + npair,
// each lane owns 2 states (n0=2*np, n0+1). float4 streaming over t with
// one-chunk register prefetch. Writes YT[dir,b,d,t] = scan_y + Dp*xc.
// grid (16, 8, 2), block 64.
// ---------------------------------------------------------------------------
__global__ __launch_bounds__(64) void k_scan(
    const float* __restrict__ DLT, const float* __restrict__ XCT,
    const float* __restrict__ BmT, const float* __restrict__ CmT,
    const float* __restrict__ A_log, const float* __restrict__ Dpar,
    float* __restrict__ YT, int l) {
  int dir = blockIdx.z, b = blockIdx.y;
  int lane = threadIdx.x;
  int np = lane & 7, ds = lane >> 3;
  int d = blockIdx.x * 8 + ds;
  int pg = l * 2 + dir;
  int n0 = np * 2;
  float A0 = -__expf(A_log[((size_t)pg * 128 + d) * 16 + n0]);
  float A1 = -__expf(A_log[((size_t)pg * 128 + d) * 16 + n0 + 1]);
  float Dv = Dpar[(size_t)pg * 128 + d];
  size_t bd = ((size_t)(dir * BATCH + b) * 128 + d) * LP;
  size_t bn = ((size_t)(dir * BATCH + b) * 16 + n0) * LP;
  const float4* dl4 = (const float4*)(DLT + bd);
  const float4* xc4 = (const float4*)(XCT + bd);
  const float4* b04 = (const float4*)(BmT + bn);
  const float4* b14 = (const float4*)(BmT + bn + LP);
  const float4* c04 = (const float4*)(CmT + bn);
  const float4* c14 = (const float4*)(CmT + bn + LP);
  float4* y4 = (float4*)(YT + bd);
  float h0 = 0.f, h1 = 0.f;
  const int NC = LP / 4;
  float4 cd = dl4[0], cx = xc4[0], cb0 = b04[0], cb1 = b14[0], cc0 = c04[0], cc1 = c14[0];
#define SCAN_STEP(DL, XC, B0, B1, C0, C1, YO)            \
  {                                                      \
    float du_ = (DL) * (XC);                             \
    h0 = fmaf(__expf((DL) * A0), h0, du_ * (B0));        \
    h1 = fmaf(__expf((DL) * A1), h1, du_ * (B1));        \
    float p_ = fmaf(h1, (C1), h0 * (C0));                \
    p_ += __shfl_xor(p_, 1);                             \
    p_ += __shfl_xor(p_, 2);                             \
    p_ += __shfl_xor(p_, 4);                             \
    (YO) = fmaf(Dv, (XC), p_);                           \
  }
  for (int i = 0; i < NC; i++) {
    float4 nd = cd, nx = cx, nb0 = cb0, nb1 = cb1, nc0 = cc0, nc1 = cc1;
    if (i + 1 < NC) {
      nd = dl4[i + 1]; nx = xc4[i + 1];
      nb0 = b04[i + 1]; nb1 = b14[i + 1];
      nc0 = c04[i + 1]; nc1 = c14[i + 1];
    }
    float4 y;
    SCAN_STEP(cd.x, cx.x, cb0.x, cb1.x, cc0.x, cc1.x, y.x);
    SCAN_STEP(cd.y, cx.y, cb0.y, cb1.y, cc0.y, cc1.y, y.y);
    SCAN_STEP(cd.z, cx.z, cb0.z, cb1.z, cc0.z, cc1.z, y.z);
    SCAN_STEP(cd.w, cx.w, cb0.w, cb1.w, cc0.w, cc1.w, y.w);
    if (np == 0) y4[i] = y;
    cd = nd; cx = nx; cb0 = nb0; cb1 = nb1; cc0 = nc0; cc1 = nc1;
  }
#undef SCAN_STEP
}

// ---------------------------------------------------------------------------
// k_out: H1 = layernorm1( H + (yf*silu(zf)) @ opw_f.T + (yr*silu(zr)) @ opw_r.T )
// yf read from YT[0] at t, yr from YT[1] at L-1-t (un-reverse).
// grid (33, 8), block 256. Tile 32 t x 128 m, K=128 staged fully for both dirs.
// ---------------------------------------------------------------------------
__global__ __launch_bounds__(256) void k_out(
    const float* __restrict__ YT, const float* __restrict__ XZ,
    const float* __restrict__ Hin, const float* __restrict__ opw,
    const float* __restrict__ n1w, const float* __restrict__ n1b,
    float* __restrict__ H1, int l) {
  int b = blockIdx.y;
  int t0 = blockIdx.x * 32;
  int tid = threadIdx.x;
  __shared__ float Af[128][33];
  __shared__ float Ar[128][33];
  __shared__ float Ws[32][144];
  for (int i = 0; i < 16; i++) {
    int e = tid + i * 256;
    int tl = e & 31, k = e >> 5;
    int t = t0 + tl;
    float vf = 0.f, vr = 0.f;
    if (t < L_SEQ) {
      vf = YT[((size_t)(0 * BATCH + b) * 128 + k) * LP + t];
      vr = YT[((size_t)(1 * BATCH + b) * 128 + k) * LP + (L_SEQ - 1 - t)];
    }
    Af[k][tl] = vf;
    Ar[k][tl] = vr;
  }
  __syncthreads();
  for (int i = 0; i < 16; i++) {
    int e = tid + i * 256;
    int k = e & 127, tl = e >> 7;
    int t = t0 + tl;
    if (t < L_SEQ) {
      float zf = XZ[((size_t)(0 * BATCH + b) * L_SEQ + t) * 256 + 128 + k];
      float zr = XZ[((size_t)(1 * BATCH + b) * L_SEQ + (L_SEQ - 1 - t)) * 256 + 128 + k];
      Af[k][tl] *= silu_f(zf);
      Ar[k][tl] *= silu_f(zr);
    }
  }
  __syncthreads();
  int tm = tid & 15, tt = tid >> 4;
  float acc[2][8] = {{0.f}};
  for (int dirp = 0; dirp < 2; dirp++) {
    const float* wsrc = opw + (size_t)(l * 2 + dirp) * 128 * 128;
    const float(*Acur)[33] = dirp ? Ar : Af;
    for (int k0 = 0; k0 < 128; k0 += 32) {
      for (int i = 0; i < 16; i++) {
        int e = tid + i * 256;
        int ki = e & 31, m = e >> 5;
        Ws[ki][m] = wsrc[(size_t)m * 128 + k0 + ki];
      }
      __syncthreads();
      for (int ki = 0; ki < 32; ki++) {
        float a0 = Acur[k0 + ki][tt * 2], a1 = Acur[k0 + ki][tt * 2 + 1];
        float w[8];
        *(float4*)&w[0] = *(const float4*)&Ws[ki][tm * 8];
        *(float4*)&w[4] = *(const float4*)&Ws[ki][tm * 8 + 4];
#pragma unroll
        for (int j = 0; j < 8; j++) {
          acc[0][j] = fmaf(a0, w[j], acc[0][j]);
          acc[1][j] = fmaf(a1, w[j], acc[1][j]);
        }
      }
      __syncthreads();
    }
  }
  const float* nw = n1w + l * 128;
  const float* nb = n1b + l * 128;
#pragma unroll
  for (int r = 0; r < 2; r++) {
    int tl = tt * 2 + r;
    int t = t0 + tl;
    float resid[8] = {0.f};
    if (t < L_SEQ) {
      const float4* hp = (const float4*)&Hin[((size_t)b * L_SEQ + t) * 128 + tm * 8];
      *(float4*)&resid[0] = hp[0];
      *(float4*)&resid[4] = hp[1];
    }
    float val[8], s1 = 0.f, s2 = 0.f;
#pragma unroll
    for (int j = 0; j < 8; j++) {
      float v = acc[r][j] + resid[j];
      val[j] = v;
      s1 += v;
      s2 += v * v;
    }
#pragma unroll
    for (int msk = 1; msk < 16; msk <<= 1) {
      s1 += __shfl_xor(s1, msk);
      s2 += __shfl_xor(s2, msk);
    }
    float mean = s1 * (1.f / 128.f);
    float rstd = rsqrtf(s2 * (1.f / 128.f) - mean * mean + 1e-5f);
    if (t < L_SEQ) {
      float* dst = &H1[((size_t)b * L_SEQ + t) * 128 + tm * 8];
#pragma unroll
      for (int j = 0; j < 8; j++)
        dst[j] = (val[j] - mean) * rstd * nw[tm * 8 + j] + nb[tm * 8 + j];
    }
  }
}

// ---------------------------------------------------------------------------
// k_ffn: H = layernorm2( h1 + relu(h1@w1.T+b1)@w2.T + b2 )
// grid (33, 8), block 256.
// ---------------------------------------------------------------------------
__global__ __launch_bounds__(256) void k_ffn(
    const float* __restrict__ H1, const float* __restrict__ w1,
    const float* __restrict__ b1, const float* __restrict__ w2,
    const float* __restrict__ b2, const float* __restrict__ n2w,
    const float* __restrict__ n2b, float* __restrict__ Hout, int l) {
  int b = blockIdx.y;
  int t0 = blockIdx.x * 32;
  int tid = threadIdx.x;
  __shared__ float At[128][33];
  __shared__ float Ut[128][33];
  __shared__ float Ws[32][144];
  for (int i = 0; i < 16; i++) {
    int e = tid + i * 256;
    int k = e & 127, tl = e >> 7;
    int t = t0 + tl;
    At[k][tl] = (t < L_SEQ) ? H1[((size_t)b * L_SEQ + t) * 128 + k] : 0.f;
  }
  __syncthreads();
  int tm = tid & 15, tt = tid >> 4;
  float acc[2][8] = {{0.f}};
  const float* w1b = w1 + (size_t)l * 128 * 128;
  for (int k0 = 0; k0 < 128; k0 += 32) {
    for (int i = 0; i < 16; i++) {
      int e = tid + i * 256;
      int ki = e & 31, m = e >> 5;
      Ws[ki][m] = w1b[(size_t)m * 128 + k0 + ki];
    }
    __syncthreads();
    for (int ki = 0; ki < 32; ki++) {
      float a0 = At[k0 + ki][tt * 2], a1 = At[k0 + ki][tt * 2 + 1];
      float w[8];
      *(float4*)&w[0] = *(const float4*)&Ws[ki][tm * 8];
      *(float4*)&w[4] = *(const float4*)&Ws[ki][tm * 8 + 4];
#pragma unroll
      for (int j = 0; j < 8; j++) {
        acc[0][j] = fmaf(a0, w[j], acc[0][j]);
        acc[1][j] = fmaf(a1, w[j], acc[1][j]);
      }
    }
    __syncthreads();
  }
#pragma unroll
  for (int r = 0; r < 2; r++) {
    int tl = tt * 2 + r;
#pragma unroll
    for (int j = 0; j < 8; j++) {
      int f = tm * 8 + j;
      float u = acc[r][j] + b1[l * 128 + f];
      Ut[f][tl] = fmaxf(u, 0.f);
      acc[r][j] = 0.f;
    }
  }
  __syncthreads();
  const float* w2b = w2 + (size_t)l * 128 * 128;
  for (int k0 = 0; k0 < 128; k0 += 32) {
    for (int i = 0; i < 16; i++) {
      int e = tid + i * 256;
      int ki = e & 31, m = e >> 5;
      Ws[ki][m] = w2b[(size_t)m * 128 + k0 + ki];
    }
    __syncthreads();
    for (int ki = 0; ki < 32; ki++) {
      float a0 = Ut[k0 + ki][tt * 2], a1 = Ut[k0 + ki][tt * 2 + 1];
      float w[8];
      *(float4*)&w[0] = *(const float4*)&Ws[ki][tm * 8];
      *(float4*)&w[4] = *(const float4*)&Ws[ki][tm * 8 + 4];
#pragma unroll
      for (int j = 0; j < 8; j++) {
        acc[0][j] = fmaf(a0, w[j], acc[0][j]);
        acc[1][j] = fmaf(a1, w[j], acc[1][j]);
      }
    }
    __syncthreads();
  }
  const float* nw = n2w + l * 128;
  const float* nb = n2b + l * 128;
#pragma unroll
  for (int r = 0; r < 2; r++) {
    int tl = tt * 2 + r;
    int t = t0 + tl;
    float val[8], s1 = 0.f, s2 = 0.f;
#pragma unroll
    for (int j = 0; j < 8; j++) {
      int m = tm * 8 + j;
      float v = acc[r][j] + b2[l * 128 + m] + At[m][tl];
      val[j] = v;
      s1 += v;
      s2 += v * v;
    }
#pragma unroll
    for (int msk = 1; msk < 16; msk <<= 1) {
      s1 += __shfl_xor(s1, msk);
      s2 += __shfl_xor(s2, msk);
    }
    float mean = s1 * (1.f / 128.f);
    float rstd = rsqrtf(s2 * (1.f / 128.f) - mean * mean + 1e-5f);
    if (t < L_SEQ) {
      float* dst = &Hout[((size_t)b * L_SEQ + t) * 128 + tm * 8];
#pragma unroll
      for (int j = 0; j < 8; j++) {
        int m = tm * 8 + j;
        dst[j] = (val[j] - mean) * rstd * nw[m] + nb[m];
      }
    }
  }
}

// ---------------------------------------------------------------------------
// k_final: out[b,p,v] = layernorm(H[b,v,:]; fnorm) @ proj_w.T + proj_b, v<1024
// grid (32, 8), block 256.
// ---------------------------------------------------------------------------
__global__ __launch_bounds__(256) void k_final(
    const float* __restrict__ Hsrc, const float* __restrict__ fw,
    const float* __restrict__ fb, const float* __restrict__ pw,
    const float* __restrict__ pb, float* __restrict__ out) {
  int b = blockIdx.y;
  int v0 = blockIdx.x * 32;
  int tid = threadIdx.x;
  __shared__ float At[128][33];
  __shared__ float Ws[32][97];
  for (int i = 0; i < 16; i++) {
    int e = tid + i * 256;
    int k = e & 127, tl = e >> 7;
    At[k][tl] = Hsrc[((size_t)b * L_SEQ + v0 + tl) * 128 + k];
  }
  __syncthreads();
  {
    int tl = tid >> 3, g = tid & 7;
    float s1 = 0.f, s2 = 0.f;
#pragma unroll
    for (int kk = 0; kk < 16; kk++) {
      float v = At[g * 16 + kk][tl];
      s1 += v;
      s2 += v * v;
    }
    s1 += __shfl_xor(s1, 1); s1 += __shfl_xor(s1, 2); s1 += __shfl_xor(s1, 4);
    s2 += __shfl_xor(s2, 1); s2 += __shfl_xor(s2, 2); s2 += __shfl_xor(s2, 4);
    float mean = s1 * (1.f / 128.f);
    float rstd = rsqrtf(s2 * (1.f / 128.f) - mean * mean + 1e-5f);
#pragma unroll
    for (int kk = 0; kk < 16; kk++) {
      int k = g * 16 + kk;
      At[k][tl] = (At[k][tl] - mean) * rstd * fw[k] + fb[k];
    }
  }
  __syncthreads();
  int tm = tid & 15, tt = tid >> 4;
  float acc[2][6] = {{0.f}};
  for (int k0 = 0; k0 < 128; k0 += 32) {
    for (int i = 0; i < 12; i++) {
      int e = tid + i * 256;
      int ki = e & 31, p = e >> 5;
      Ws[ki][p] = pw[(size_t)p * 128 + k0 + ki];
    }
    __syncthreads();
    for (int ki = 0; ki < 32; ki++) {
      float a0 = At[k0 + ki][tt * 2], a1 = At[k0 + ki][tt * 2 + 1];
#pragma unroll
      for (int j = 0; j < 6; j++) {
        float w = Ws[ki][tm + j * 16];
        acc[0][j] = fmaf(a0, w, acc[0][j]);
        acc[1][j] = fmaf(a1, w, acc[1][j]);
      }
    }
    __syncthreads();
  }
#pragma unroll
  for (int r = 0; r < 2; r++) {
    int v = v0 + tt * 2 + r;
#pragma unroll
    for (int j = 0; j < 6; j++) {
      int p = tm + j * 16;
      out[((size_t)b * 96 + p) * 1024 + v] = acc[r][j] + pb[p];
    }
  }
}

// ---------------------------------------------------------------------------
extern "C" void kernel_launch(void* const* d_in, const int* in_sizes, int n_in,
                              void* d_out, int out_size, void* d_ws, size_t ws_size,
                              hipStream_t stream) {
  (void)in_sizes; (void)n_in; (void)out_size; (void)ws_size;
  const float* x_enc  = (const float*)d_in[0];
  const float* x_mark = (const float*)d_in[1];
  const float* emb_w  = (const float*)d_in[4];
  const float* emb_b  = (const float*)d_in[5];
  const float* ipw    = (const float*)d_in[6];
  const float* cw     = (const float*)d_in[7];
  const float* cb     = (const float*)d_in[8];
  const float* xpw    = (const float*)d_in[9];
  const float* dpw    = (const float*)d_in[10];
  const float* dpb    = (const float*)d_in[11];
  const float* A_log  = (const float*)d_in[12];
  const float* Dpar   = (const float*)d_in[13];
  const float* opw    = (const float*)d_in[14];
  const float* n1w    = (const float*)d_in[15];
  const float* n1b    = (const float*)d_in[16];
  const float* n2w    = (const float*)d_in[17];
  const float* n2b    = (const float*)d_in[18];
  const float* fw1    = (const float*)d_in[19];
  const float* fb1    = (const float*)d_in[20];
  const float* fw2    = (const float*)d_in[21];
  const float* fb2    = (const float*)d_in[22];
  const float* fnw    = (const float*)d_in[23];
  const float* fnb    = (const float*)d_in[24];
  const float* pw     = (const float*)d_in[25];
  const float* pb     = (const float*)d_in[26];

  float* ws  = (float*)d_ws;
  float* H   = ws + OFF_H;
  float* H1  = ws + OFF_H1;
  float* XZ  = ws + OFF_XZ;
  float* XCT = ws + OFF_XCT;
  float* DLT = ws + OFF_DLT;
  float* BmT = ws + OFF_BMT;
  float* CmT = ws + OFF_CMT;
  float* YT  = ws + OFF_YT;

  k_embed<<<dim3(33, 8), 256, 0, stream>>>(x_enc, x_mark, emb_w, emb_b, H);
  for (int l = 0; l < 2; l++) {
    k_xz<<<dim3(33, 8, 2), 256, 0, stream>>>(H, ipw, XZ, l);
    k_mid<<<dim3(17, 8, 2), 256, 0, stream>>>(XZ, cw, cb, xpw, dpw, dpb,
                                              XCT, DLT, BmT, CmT, l);
    k_scan<<<dim3(16, 8, 2), 64, 0, stream>>>(DLT, XCT, BmT, CmT, A_log, Dpar, YT, l);
    k_out<<<dim3(33, 8), 256, 0, stream>>>(YT, XZ, H, opw, n1w, n1b, H1, l);
    k_ffn<<<dim3(33, 8), 256, 0, stream>>>(H1, fw1, fb1, fw2, fb2, n2w, n2b, H, l);
  }
  k_final<<<dim3(32, 8), 256, 0, stream>>>(H, fnw, fnb, pw, pb, (float*)d_out);
}